// Round 4
// baseline (226.338 us; speedup 1.0000x reference)
//
#include <hip/hip_runtime.h>

#define B_SZ  32
#define IN_D  2048
#define OUT_D 2048
#define K_N   8
#define H_D   512
#define NPART 64

// ---------------------------------------------------------------------------
// K1a: partial[m][j] = sum_{i in stripe m} cond[i] * w1[i][j]
// 64 blocks x 256 threads; block m handles 32 rows of w1 (coalesced, fully
// unrolled so all 64 loads pipeline).
// ---------------------------------------------------------------------------
__global__ void k1_partial(const float* __restrict__ cond,
                           const float* __restrict__ w1,
                           float* __restrict__ ws) {
    const int m     = blockIdx.x;
    const int tid   = threadIdx.x;
    const int ibase = m * (IN_D / NPART);
    float p0 = 0.f, p1 = 0.f;
    #pragma unroll
    for (int ii = 0; ii < IN_D / NPART; ++ii) {
        const float c = cond[ibase + ii];
        const float* row = w1 + (size_t)(ibase + ii) * H_D;
        p0 = fmaf(c, row[tid], p0);
        p1 = fmaf(c, row[tid + 256], p1);
    }
    float* part = ws + 1024;
    part[(size_t)m * H_D + tid]       = p0;
    part[(size_t)m * H_D + tid + 256] = p1;
}

// ---------------------------------------------------------------------------
// K1b: h = relu(b1 + sum_m partial[m]); scores = h @ w2 + b2; softmax -> ws[0..7]
// 1 block x 512 threads; every thread owns one h element and its w2 row,
// wave shuffle-reduce then tiny final pass.
// ---------------------------------------------------------------------------
__global__ void k1_scores(const float* __restrict__ b1,
                          const float* __restrict__ w2,
                          const float* __restrict__ b2,
                          float* __restrict__ ws) {
    __shared__ float sred[8][K_N];
    const int tid = threadIdx.x;          // 0..511
    const float* part = ws + 1024;
    float acc = b1[tid];
    #pragma unroll
    for (int m = 0; m < NPART; ++m) acc += part[(size_t)m * H_D + tid];
    const float h = fmaxf(acc, 0.f);

    const float* wr = w2 + (size_t)tid * K_N;
    float s[K_N];
    #pragma unroll
    for (int k = 0; k < K_N; ++k) s[k] = h * wr[k];

    #pragma unroll
    for (int k = 0; k < K_N; ++k) {
        #pragma unroll
        for (int d = 1; d < 64; d <<= 1) s[k] += __shfl_xor(s[k], d, 64);
    }
    if ((tid & 63) == 0) {
        const int w = tid >> 6;           // 0..7
        #pragma unroll
        for (int k = 0; k < K_N; ++k) sred[w][k] = s[k];
    }
    __syncthreads();
    if (tid == 0) {
        float sc[K_N];
        #pragma unroll
        for (int k = 0; k < K_N; ++k) {
            float v = b2[k];
            #pragma unroll
            for (int w = 0; w < 8; ++w) v += sred[w][k];
            sc[k] = v;
        }
        float mx = -1e30f;
        #pragma unroll
        for (int k = 0; k < K_N; ++k) mx = fmaxf(mx, sc[k]);
        float sum = 0.f;
        #pragma unroll
        for (int k = 0; k < K_N; ++k) { sc[k] = __expf(sc[k] - mx); sum += sc[k]; }
        const float inv = 1.f / sum;
        #pragma unroll
        for (int k = 0; k < K_N; ++k) ws[k] = sc[k] * inv;
    }
}

// ---------------------------------------------------------------------------
// K2: main. One output column per block (2048 blocks x 256 threads).
// Thread t owns i in [8t, 8t+8): aggregates the 8 expert weight chunks into
// 8 registers (weights stream from HBM exactly once, float4-coalesced),
// FMAs against x (L2-resident), then one padded-LDS reduction sweep.
// Register budget ~80 VGPR -> no spill under the 128 cap (256 thr, 4 wv/EU).
// ---------------------------------------------------------------------------
__global__ __launch_bounds__(256, 4) void k2_main(
    const float* __restrict__ x,
    const float* __restrict__ kw,
    const float* __restrict__ kb,
    const float* __restrict__ ws,
    float* __restrict__ out) {
    __shared__ float red[B_SZ][257];   // [batch][thread], +1 pad: conflict-free
    __shared__ float fin[8][33];
    const int tid = threadIdx.x;
    const int o   = blockIdx.x;
    const int i0  = tid * 8;

    float a[K_N];
    #pragma unroll
    for (int k = 0; k < K_N; ++k) a[k] = ws[k];

    // Aggregate expert weights for this thread's 8-element i-chunk.
    float wa[8];
    #pragma unroll
    for (int j = 0; j < 8; ++j) wa[j] = 0.f;
    #pragma unroll
    for (int k = 0; k < K_N; ++k) {
        const float* p = kw + ((size_t)k * OUT_D + o) * IN_D + i0;
        float wv[8];
        *(float4*)&wv[0] = *(const float4*)(p);
        *(float4*)&wv[4] = *(const float4*)(p + 4);
        const float ak = a[k];
        #pragma unroll
        for (int j = 0; j < 8; ++j) wa[j] = fmaf(ak, wv[j], wa[j]);
    }

    // Dot with x for all 32 batches (x is L2-hot: 256 KB total).
    float acc[B_SZ];
    #pragma unroll
    for (int b = 0; b < B_SZ; ++b) {
        const float* xp = x + (size_t)b * IN_D + i0;
        float xv[8];
        *(float4*)&xv[0] = *(const float4*)(xp);
        *(float4*)&xv[4] = *(const float4*)(xp + 4);
        float s = 0.f;
        #pragma unroll
        for (int j = 0; j < 8; ++j) s = fmaf(wa[j], xv[j], s);
        acc[b] = s;
    }

    // Single LDS reduction sweep over the 256 threads.
    #pragma unroll
    for (int j = 0; j < B_SZ; ++j) red[j][tid] = acc[j];
    __syncthreads();
    {
        const int r = tid >> 5;   // 0..7
        const int b = tid & 31;
        float s = 0.f;
        #pragma unroll
        for (int c = 0; c < 32; ++c) s += red[b][r * 32 + c];
        fin[r][b] = s;
    }
    __syncthreads();
    if (tid < B_SZ) {
        float tot = 0.f;
        #pragma unroll
        for (int rr = 0; rr < 8; ++rr) tot += fin[rr][tid];
        float aggb = 0.f;
        #pragma unroll
        for (int k = 0; k < K_N; ++k) aggb = fmaf(a[k], kb[(size_t)k * OUT_D + o], aggb);
        out[(size_t)tid * OUT_D + o] = tot + aggb;
    }
}

extern "C" void kernel_launch(void* const* d_in, const int* in_sizes, int n_in,
                              void* d_out, int out_size, void* d_ws, size_t ws_size,
                              hipStream_t stream) {
    (void)in_sizes; (void)n_in; (void)out_size; (void)ws_size;
    const float* x    = (const float*)d_in[0];
    const float* cond = (const float*)d_in[1];
    const float* w1   = (const float*)d_in[2];
    const float* b1   = (const float*)d_in[3];
    const float* w2   = (const float*)d_in[4];
    const float* b2   = (const float*)d_in[5];
    const float* kw   = (const float*)d_in[6];
    const float* kb   = (const float*)d_in[7];
    float* out = (float*)d_out;
    float* ws  = (float*)d_ws;

    k1_partial<<<NPART, 256, 0, stream>>>(cond, w1, ws);
    k1_scores<<<1, H_D, 0, stream>>>(b1, w2, b2, ws);
    k2_main<<<OUT_D, 256, 0, stream>>>(x, kw, kb, ws, out);
}